// Round 2
// baseline (8527.216 us; speedup 1.0000x reference)
//
#include <hip/hip_runtime.h>
#include <hip/hip_fp16.h>
#include <cstdint>

typedef _Float16 h2 __attribute__((ext_vector_type(2)));
typedef _Float16 h8 __attribute__((ext_vector_type(8)));
typedef float    f4 __attribute__((ext_vector_type(4)));
typedef uint32_t u4 __attribute__((ext_vector_type(4)));

#define BATCH 64
#define TSTEPS 1024
#define DDIM 512
#define HDIM 512

static __device__ __forceinline__ float fdot2(uint32_t w, uint32_t h, float acc) {
  return __builtin_amdgcn_fdot2(__builtin_bit_cast(h2, w), __builtin_bit_cast(h2, h), acc, false);
}

// ---------------------------------------------------------------------------
// prep: f16 weight conversion, pair-transposed Whh, bias sums. (unchanged)
// ---------------------------------------------------------------------------
__global__ void prep_kernel(const float* __restrict__ Wih_f, const float* __restrict__ Whh_f,
                            const float* __restrict__ bih_f, const float* __restrict__ bhh_f,
                            const float* __restrict__ Wih_b, const float* __restrict__ Whh_b,
                            const float* __restrict__ bih_b, const float* __restrict__ bhh_b,
                            _Float16* __restrict__ wi16, uint32_t* __restrict__ whT,
                            float* __restrict__ bsum) {
  int i = blockIdx.x * 256 + threadIdx.x;
  if (i < 2 * 512 * 512) {
    const float* s = (i < 512 * 512) ? Wih_f : Wih_b;
    wi16[i] = (_Float16)s[i & (512 * 512 - 1)];
  }
  if (i < 2 * 256 * 512) {
    int d = i >> 17; int rem = i & ((1 << 17) - 1);
    int kp = rem >> 9; int j = rem & 511;
    const float* W = d ? Whh_b : Whh_f;
    h2 p; p[0] = (_Float16)W[j * 512 + 2 * kp]; p[1] = (_Float16)W[j * 512 + 2 * kp + 1];
    whT[i] = __builtin_bit_cast(uint32_t, p);
  }
  if (i < 2 * 512) {
    int d = i >> 9, j = i & 511;
    bsum[i] = d ? (bih_b[j] + bhh_b[j]) : (bih_f[j] + bhh_f[j]);
  }
}

__global__ void clear_flags(uint32_t* __restrict__ flg) {
  flg[threadIdx.x] = 0;   // 512 flags; must be re-cleared every launch (ws persists)
}

// ---------------------------------------------------------------------------
// xp_gemm (unchanged): xp[dir][m][n] f16, m in processing order.
// ---------------------------------------------------------------------------
__global__ __launch_bounds__(256) void xp_gemm(const float* __restrict__ x,
                                               const _Float16* __restrict__ wi,
                                               const float* __restrict__ bsum,
                                               _Float16* __restrict__ xp) {
  __shared__ _Float16 As[128][40];
  __shared__ _Float16 Bs[128][40];
  const int mt = blockIdx.x, nt = blockIdx.y, dir = blockIdx.z;
  const int m0 = mt * 128, n0 = nt * 128;
  const int tid = threadIdx.x;
  const int lane = tid & 63, w = tid >> 6;
  const int wr = w >> 1, wc = w & 1;
  const int ra = tid >> 1, hf = tid & 1;

  const int mrow = m0 + ra;
  const int bb = mrow >> 10, pp = mrow & 1023;
  const int srow = dir ? ((bb << 10) + (1023 - pp)) : mrow;
  const float*    xbase = x + (size_t)srow * 512 + hf * 16;
  const _Float16* wbase = wi + (size_t)dir * 512 * 512 + (size_t)(n0 + ra) * 512 + hf * 16;

  f4 acc[4][4];
  #pragma unroll
  for (int a = 0; a < 4; ++a)
    #pragma unroll
    for (int b = 0; b < 4; ++b) acc[a][b] = (f4)0.f;

  for (int k0 = 0; k0 < 512; k0 += 32) {
    f4 x0 = *(const f4*)(xbase + k0);
    f4 x1 = *(const f4*)(xbase + k0 + 4);
    f4 x2 = *(const f4*)(xbase + k0 + 8);
    f4 x3 = *(const f4*)(xbase + k0 + 12);
    h8 b0 = *(const h8*)(wbase + k0);
    h8 b1 = *(const h8*)(wbase + k0 + 8);
    h8 a0, a1;
    #pragma unroll
    for (int u = 0; u < 4; ++u) {
      a0[u] = (_Float16)x0[u]; a0[4 + u] = (_Float16)x1[u];
      a1[u] = (_Float16)x2[u]; a1[4 + u] = (_Float16)x3[u];
    }
    __syncthreads();
    *(h8*)&As[ra][hf * 16]     = a0;
    *(h8*)&As[ra][hf * 16 + 8] = a1;
    *(h8*)&Bs[ra][hf * 16]     = b0;
    *(h8*)&Bs[ra][hf * 16 + 8] = b1;
    __syncthreads();
    h8 af[4], bf[4];
    #pragma unroll
    for (int fm = 0; fm < 4; ++fm)
      af[fm] = *(const h8*)&As[wr * 64 + fm * 16 + (lane & 15)][(lane >> 4) * 8];
    #pragma unroll
    for (int fn = 0; fn < 4; ++fn)
      bf[fn] = *(const h8*)&Bs[wc * 64 + fn * 16 + (lane & 15)][(lane >> 4) * 8];
    #pragma unroll
    for (int fm = 0; fm < 4; ++fm)
      #pragma unroll
      for (int fn = 0; fn < 4; ++fn)
        acc[fm][fn] = __builtin_amdgcn_mfma_f32_16x16x32_f16(af[fm], bf[fn], acc[fm][fn], 0, 0, 0);
  }

  float bsv[4];
  #pragma unroll
  for (int fn = 0; fn < 4; ++fn)
    bsv[fn] = bsum[dir * 512 + n0 + wc * 64 + fn * 16 + (lane & 15)];
  #pragma unroll
  for (int fm = 0; fm < 4; ++fm)
    #pragma unroll
    for (int fn = 0; fn < 4; ++fn)
      #pragma unroll
      for (int u = 0; u < 4; ++u) {
        int m = m0 + wr * 64 + fm * 16 + (lane >> 4) * 4 + u;
        int n = n0 + wc * 64 + fn * 16 + (lane & 15);
        xp[((size_t)dir << 25) + (size_t)m * 512 + n] = (_Float16)(acc[fm][fn][u] + bsv[fn]);
      }
}

// ---------------------------------------------------------------------------
// rnn_rec: 256 WGs (one per (chain, H-half)), 1024 threads, ALL weights in VGPRs.
//   Chain c's two WGs placed on the SAME XCD (bids x+16g and x+16g+8, x=c&7).
//   thread l: ks = l>>7 (k-eighth, 32 u32 pairs), r = l&127;
//             outputs j = half*256 + r and half*256 + 128 + r.
//   Per step: 8x{ds_read_b128 h; 8 fdot2}, psum 8-way reduce in LDS, tanh,
//             cross-WG h-half exchange via L2 (release/acquire, parity slots).
// ---------------------------------------------------------------------------
__global__ __launch_bounds__(1024, 4) void rnn_rec(const _Float16* __restrict__ xp,
                                                   const uint32_t* __restrict__ whT,
                                                   uint32_t* __restrict__ gh,
                                                   uint32_t* __restrict__ flg,
                                                   float* __restrict__ out) {
  __shared__ uint32_t hl[256];        // full h as f16 pairs (kp = k/2 index 0..255)
  __shared__ float psum[8][264];

  const int bid = blockIdx.x;
  const int half = (bid >> 3) & 1;                     // same-XCD pairing
  const int c = (bid & 7) | ((bid >> 4) << 3);         // chain 0..127
  const int dir = c & 1, b = c >> 1;
  const int l = threadIdx.x;
  const int ks = l >> 7, r = l & 127;

  // weights: 64 u32 per lane, all in registers
  const uint32_t* wb = whT + dir * (256 * 512) + (ks * 32) * 512 + half * 256 + r;
  uint32_t w0[32], w1[32];
  #pragma unroll
  for (int p = 0; p < 32; ++p) w0[p] = wb[p * 512];
  #pragma unroll
  for (int p = 0; p < 32; ++p) w1[p] = wb[p * 512 + 128];

  if (l < 256) hl[l] = 0;
  __syncthreads();

  const _Float16* xpp = xp + ((size_t)dir << 25) + ((size_t)b << 19) + half * 256;
  float* op = out + (((size_t)(b * 2 + dir)) << 19) + half * 256;

  for (int t = 0; t < TSTEPS; ++t) {
    float xpv = 0.f;
    if (l < 256) xpv = (float)xpp[(size_t)t * 512 + l];

    float acc0 = 0.f, acc1 = 0.f;
    const uint32_t* hq = hl + ks * 32;
    #pragma unroll
    for (int cb = 0; cb < 8; ++cb) {
      u4 hv4 = *(const u4*)(hq + cb * 4);              // wave-uniform broadcast
      #pragma unroll
      for (int i = 0; i < 4; ++i) {
        acc0 = fdot2(w0[cb * 4 + i], hv4[i], acc0);
        acc1 = fdot2(w1[cb * 4 + i], hv4[i], acc1);
      }
    }
    psum[ks][r]       = acc0;
    psum[ks][r + 128] = acc1;
    __syncthreads();                                    // B1

    if (l < 256) {
      float s = xpv;
      #pragma unroll
      for (int k2 = 0; k2 < 8; ++k2) s += psum[k2][l];
      float e = __expf(2.f * s);
      float hv = 1.f - 2.f * __builtin_amdgcn_rcpf(e + 1.f);   // tanh
      op[(size_t)t * 512 + l] = hv;
      ((_Float16*)hl)[half * 256 + l] = (_Float16)hv;
    }
    __syncthreads();                                    // B2 (own half in LDS)

    if (t < TSTEPS - 1) {
      const int par = t & 1;
      if (l < 64) {
        // publish own half: wave 0 stores 128 u32, lane 0 releases flag
        uint32_t d0 = hl[half * 128 + l];
        uint32_t d1 = hl[half * 128 + 64 + l];
        uint32_t* dst = gh + ((((c << 1) | par) << 1 | half) << 7);
        __hip_atomic_store(dst + l,      d0, __ATOMIC_RELAXED, __HIP_MEMORY_SCOPE_AGENT);
        __hip_atomic_store(dst + 64 + l, d1, __ATOMIC_RELAXED, __HIP_MEMORY_SCOPE_AGENT);
        if (l == 0)
          __hip_atomic_store(&flg[(((c << 1) | par) << 1) | half], (uint32_t)(t + 1),
                             __ATOMIC_RELEASE, __HIP_MEMORY_SCOPE_AGENT);
      } else if (l >= 512 && l < 576) {
        // stage partner half: wave 8 spins, loads 128 u32, writes LDS
        const int ph = half ^ 1;
        const int li = l - 512;
        uint32_t* pf = &flg[(((c << 1) | par) << 1) | ph];
        while (__hip_atomic_load(pf, __ATOMIC_ACQUIRE, __HIP_MEMORY_SCOPE_AGENT) < (uint32_t)(t + 1))
          __builtin_amdgcn_s_sleep(2);
        const uint32_t* src = gh + ((((c << 1) | par) << 1 | ph) << 7);
        uint32_t d0 = __hip_atomic_load(src + li,      __ATOMIC_RELAXED, __HIP_MEMORY_SCOPE_AGENT);
        uint32_t d1 = __hip_atomic_load(src + 64 + li, __ATOMIC_RELAXED, __HIP_MEMORY_SCOPE_AGENT);
        hl[ph * 128 + li]      = d0;
        hl[ph * 128 + 64 + li] = d1;
      }
    }
    __syncthreads();                                    // B3 (full h(t) in LDS)
  }
}

// ---------------------------------------------------------------------------
extern "C" void kernel_launch(void* const* d_in, const int* in_sizes, int n_in,
                              void* d_out, int out_size, void* d_ws, size_t ws_size,
                              hipStream_t stream) {
  const float* x     = (const float*)d_in[0];
  const float* Wih_f = (const float*)d_in[1];
  const float* Whh_f = (const float*)d_in[2];
  const float* bih_f = (const float*)d_in[3];
  const float* bhh_f = (const float*)d_in[4];
  const float* Wih_b = (const float*)d_in[5];
  const float* Whh_b = (const float*)d_in[6];
  const float* bih_b = (const float*)d_in[7];
  const float* bhh_b = (const float*)d_in[8];

  char* ws = (char*)d_ws;
  _Float16* xp16 = (_Float16*)ws;                 // 128 MB
  _Float16* wi16 = (_Float16*)(ws + 134217728);   // 1 MB
  uint32_t* whT  = (uint32_t*)(ws + 135266304);   // 1 MB
  float*    bsum = (float*)(ws + 136314880);      // 4 KB
  uint32_t* gh   = (uint32_t*)(ws + 136318976);   // 256 KB exchange slots
  uint32_t* flg  = (uint32_t*)(ws + 136581120);   // 2 KB flags
  float* out = (float*)d_out;

  clear_flags<<<1, 512, 0, stream>>>(flg);
  prep_kernel<<<2048, 256, 0, stream>>>(Wih_f, Whh_f, bih_f, bhh_f,
                                        Wih_b, Whh_b, bih_b, bhh_b, wi16, whT, bsum);
  dim3 g(512, 4, 2);
  xp_gemm<<<g, 256, 0, stream>>>(x, wi16, bsum, xp16);

  void* args[] = {&xp16, &whT, &gh, &flg, &out};
  hipLaunchCooperativeKernel((const void*)rnn_rec, dim3(256), dim3(1024), args, 0, stream);
}

// Round 3
// 2958.719 us; speedup vs baseline: 2.8821x; 2.8821x over previous
//
#include <hip/hip_runtime.h>
#include <hip/hip_fp16.h>
#include <cstdint>

typedef _Float16 h2 __attribute__((ext_vector_type(2)));
typedef _Float16 h8 __attribute__((ext_vector_type(8)));
typedef float    f4 __attribute__((ext_vector_type(4)));
typedef uint32_t u4 __attribute__((ext_vector_type(4)));

#define BATCH 64
#define TSTEPS 1024
#define DDIM 512
#define HDIM 512

static __device__ __forceinline__ float fdot2(uint32_t w, uint32_t h, float acc) {
  return __builtin_amdgcn_fdot2(__builtin_bit_cast(h2, w), __builtin_bit_cast(h2, h), acc, false);
}

// ---------------------------------------------------------------------------
// prep: f16 weight conversion, pair-transposed Whh, bias sums.
//   wi16[dir][n][k] f16; whT[dir][kp][j] u32 (f16x2 of Whh[dir][j][2kp..2kp+1]);
//   bsum[dir][j] f32.
// ---------------------------------------------------------------------------
__global__ void prep_kernel(const float* __restrict__ Wih_f, const float* __restrict__ Whh_f,
                            const float* __restrict__ bih_f, const float* __restrict__ bhh_f,
                            const float* __restrict__ Wih_b, const float* __restrict__ Whh_b,
                            const float* __restrict__ bih_b, const float* __restrict__ bhh_b,
                            _Float16* __restrict__ wi16, uint32_t* __restrict__ whT,
                            float* __restrict__ bsum) {
  int i = blockIdx.x * 256 + threadIdx.x;
  if (i < 2 * 512 * 512) {
    const float* s = (i < 512 * 512) ? Wih_f : Wih_b;
    wi16[i] = (_Float16)s[i & (512 * 512 - 1)];
  }
  if (i < 2 * 256 * 512) {
    int d = i >> 17; int rem = i & ((1 << 17) - 1);
    int kp = rem >> 9; int j = rem & 511;
    const float* W = d ? Whh_b : Whh_f;
    h2 p; p[0] = (_Float16)W[j * 512 + 2 * kp]; p[1] = (_Float16)W[j * 512 + 2 * kp + 1];
    whT[i] = __builtin_bit_cast(uint32_t, p);
  }
  if (i < 2 * 512) {
    int d = i >> 9, j = i & 511;
    bsum[i] = d ? (bih_b[j] + bhh_b[j]) : (bih_f[j] + bhh_f[j]);
  }
}

// ---------------------------------------------------------------------------
// xp_gemm (unchanged): xp[dir][m][n] f16, m = b*1024 + t (processing order).
// ---------------------------------------------------------------------------
__global__ __launch_bounds__(256) void xp_gemm(const float* __restrict__ x,
                                               const _Float16* __restrict__ wi,
                                               const float* __restrict__ bsum,
                                               _Float16* __restrict__ xp) {
  __shared__ _Float16 As[128][40];
  __shared__ _Float16 Bs[128][40];
  const int mt = blockIdx.x, nt = blockIdx.y, dir = blockIdx.z;
  const int m0 = mt * 128, n0 = nt * 128;
  const int tid = threadIdx.x;
  const int lane = tid & 63, w = tid >> 6;
  const int wr = w >> 1, wc = w & 1;
  const int ra = tid >> 1, hf = tid & 1;

  const int mrow = m0 + ra;
  const int bb = mrow >> 10, pp = mrow & 1023;
  const int srow = dir ? ((bb << 10) + (1023 - pp)) : mrow;
  const float*    xbase = x + (size_t)srow * 512 + hf * 16;
  const _Float16* wbase = wi + (size_t)dir * 512 * 512 + (size_t)(n0 + ra) * 512 + hf * 16;

  f4 acc[4][4];
  #pragma unroll
  for (int a = 0; a < 4; ++a)
    #pragma unroll
    for (int b = 0; b < 4; ++b) acc[a][b] = (f4)0.f;

  for (int k0 = 0; k0 < 512; k0 += 32) {
    f4 x0 = *(const f4*)(xbase + k0);
    f4 x1 = *(const f4*)(xbase + k0 + 4);
    f4 x2 = *(const f4*)(xbase + k0 + 8);
    f4 x3 = *(const f4*)(xbase + k0 + 12);
    h8 b0 = *(const h8*)(wbase + k0);
    h8 b1 = *(const h8*)(wbase + k0 + 8);
    h8 a0, a1;
    #pragma unroll
    for (int u = 0; u < 4; ++u) {
      a0[u] = (_Float16)x0[u]; a0[4 + u] = (_Float16)x1[u];
      a1[u] = (_Float16)x2[u]; a1[4 + u] = (_Float16)x3[u];
    }
    __syncthreads();
    *(h8*)&As[ra][hf * 16]     = a0;
    *(h8*)&As[ra][hf * 16 + 8] = a1;
    *(h8*)&Bs[ra][hf * 16]     = b0;
    *(h8*)&Bs[ra][hf * 16 + 8] = b1;
    __syncthreads();
    h8 af[4], bf[4];
    #pragma unroll
    for (int fm = 0; fm < 4; ++fm)
      af[fm] = *(const h8*)&As[wr * 64 + fm * 16 + (lane & 15)][(lane >> 4) * 8];
    #pragma unroll
    for (int fn = 0; fn < 4; ++fn)
      bf[fn] = *(const h8*)&Bs[wc * 64 + fn * 16 + (lane & 15)][(lane >> 4) * 8];
    #pragma unroll
    for (int fm = 0; fm < 4; ++fm)
      #pragma unroll
      for (int fn = 0; fn < 4; ++fn)
        acc[fm][fn] = __builtin_amdgcn_mfma_f32_16x16x32_f16(af[fm], bf[fn], acc[fm][fn], 0, 0, 0);
  }

  float bsv[4];
  #pragma unroll
  for (int fn = 0; fn < 4; ++fn)
    bsv[fn] = bsum[dir * 512 + n0 + wc * 64 + fn * 16 + (lane & 15)];
  #pragma unroll
  for (int fm = 0; fm < 4; ++fm)
    #pragma unroll
    for (int fn = 0; fn < 4; ++fn)
      #pragma unroll
      for (int u = 0; u < 4; ++u) {
        int m = m0 + wr * 64 + fm * 16 + (lane >> 4) * 4 + u;
        int n = n0 + wc * 64 + fn * 16 + (lane & 15);
        xp[((size_t)dir << 25) + (size_t)m * 512 + n] = (_Float16)(acc[fm][fn][u] + bsv[fn]);
      }
}

// ---------------------------------------------------------------------------
// rnn_rec: ONE workgroup per chain (128 WGs, 1024 threads, 1 block/CU ->
//   4 waves/SIMD -> per-wave register budget 512).
//   ALL Whh weights in VGPRs: lane l (ks = l>>7, r = l&127) holds
//   w0..w3[32] = Whh pairs (kp = ks*32..ks*32+31) for outputs
//   j = {r, 128+r, 256+r, 384+r}  -> 128 u32/lane, 512 KB/CU total.
//   Per step: 8 wave-uniform ds_read_b128 of h + 128 fdot2/lane,
//   8-way psum reduce in LDS, tanh on 512 lanes, 2 barriers. No LDS weights.
// ---------------------------------------------------------------------------
__global__ __launch_bounds__(1024, 4) void rnn_rec(const _Float16* __restrict__ xp,
                                                   const uint32_t* __restrict__ whT,
                                                   float* __restrict__ out) {
  __shared__ uint32_t hl[256];         // h(t) as 256 f16x2 pairs
  __shared__ float psum[8][512];       // per-k-eighth partial sums

  const int bid = blockIdx.x;
  const int dir = bid & 1, b = bid >> 1;
  const int l = threadIdx.x;
  const int ks = l >> 7, r = l & 127;

  // ---- load all weights into registers (coalesced: r consecutive) ----
  const uint32_t* wb = whT + dir * (256 * 512) + (ks * 32) * 512 + r;
  uint32_t w0[32], w1[32], w2[32], w3[32];
  #pragma unroll
  for (int p = 0; p < 32; ++p) w0[p] = wb[p * 512];
  #pragma unroll
  for (int p = 0; p < 32; ++p) w1[p] = wb[p * 512 + 128];
  #pragma unroll
  for (int p = 0; p < 32; ++p) w2[p] = wb[p * 512 + 256];
  #pragma unroll
  for (int p = 0; p < 32; ++p) w3[p] = wb[p * 512 + 384];

  if (l < 256) hl[l] = 0;
  __syncthreads();

  const _Float16* xpp = xp + ((size_t)dir << 25) + ((size_t)b << 19);
  float* op = out + (((size_t)(b * 2 + dir)) << 19);

  for (int t = 0; t < TSTEPS; ++t) {
    // prefetch xp(t) early; consumed after the dot-product loop
    float xpv = 0.f;
    if (l < 512) xpv = (float)xpp[(size_t)t * 512 + l];

    float a0 = 0.f, a1 = 0.f, a2 = 0.f, a3 = 0.f;
    const uint32_t* hq = hl + ks * 32;
    #pragma unroll
    for (int cb = 0; cb < 8; ++cb) {
      u4 hv4 = *(const u4*)(hq + cb * 4);          // wave-uniform broadcast
      #pragma unroll
      for (int i = 0; i < 4; ++i) {
        uint32_t hw = hv4[i];
        a0 = fdot2(w0[cb * 4 + i], hw, a0);
        a1 = fdot2(w1[cb * 4 + i], hw, a1);
        a2 = fdot2(w2[cb * 4 + i], hw, a2);
        a3 = fdot2(w3[cb * 4 + i], hw, a3);
      }
    }
    // psum writes: lanes consecutive within each row -> conflict-free
    psum[ks][r]       = a0;
    psum[ks][r + 128] = a1;
    psum[ks][r + 256] = a2;
    psum[ks][r + 384] = a3;
    __syncthreads();                               // B1

    if (l < 512) {
      float s = xpv;
      #pragma unroll
      for (int k2 = 0; k2 < 8; ++k2) s += psum[k2][l];
      float e = __expf(2.f * s);
      float hv = 1.f - 2.f * __builtin_amdgcn_rcpf(e + 1.f);   // tanh(s)
      op[(size_t)t * 512 + l] = hv;
      ((_Float16*)hl)[l] = (_Float16)hv;
    }
    __syncthreads();                               // B2: h(t) ready in LDS
  }
}

// ---------------------------------------------------------------------------
extern "C" void kernel_launch(void* const* d_in, const int* in_sizes, int n_in,
                              void* d_out, int out_size, void* d_ws, size_t ws_size,
                              hipStream_t stream) {
  const float* x     = (const float*)d_in[0];
  const float* Wih_f = (const float*)d_in[1];
  const float* Whh_f = (const float*)d_in[2];
  const float* bih_f = (const float*)d_in[3];
  const float* bhh_f = (const float*)d_in[4];
  const float* Wih_b = (const float*)d_in[5];
  const float* Whh_b = (const float*)d_in[6];
  const float* bih_b = (const float*)d_in[7];
  const float* bhh_b = (const float*)d_in[8];

  char* ws = (char*)d_ws;
  _Float16* xp16 = (_Float16*)ws;                 // 128 MB
  _Float16* wi16 = (_Float16*)(ws + 134217728);   // 1 MB
  uint32_t* whT  = (uint32_t*)(ws + 135266304);   // 1 MB
  float*    bsum = (float*)(ws + 136314880);      // 4 KB
  float* out = (float*)d_out;

  prep_kernel<<<2048, 256, 0, stream>>>(Wih_f, Whh_f, bih_f, bhh_f,
                                        Wih_b, Whh_b, bih_b, bhh_b, wi16, whT, bsum);
  dim3 g(512, 4, 2);
  xp_gemm<<<g, 256, 0, stream>>>(x, wi16, bsum, xp16);

  rnn_rec<<<128, 1024, 0, stream>>>(xp16, whT, out);
}

// Round 4
// 1643.217 us; speedup vs baseline: 5.1893x; 1.8006x over previous
//
#include <hip/hip_runtime.h>
#include <hip/hip_fp16.h>
#include <cstdint>

typedef _Float16 h2 __attribute__((ext_vector_type(2)));
typedef _Float16 h8 __attribute__((ext_vector_type(8)));
typedef float    f4 __attribute__((ext_vector_type(4)));
typedef uint32_t u4 __attribute__((ext_vector_type(4)));

#define BATCH 64
#define TSTEPS 1024
#define DDIM 512
#define HDIM 512

static __device__ __forceinline__ float fdot2(uint32_t w, uint32_t h, float acc) {
  return __builtin_amdgcn_fdot2(__builtin_bit_cast(h2, w), __builtin_bit_cast(h2, h), acc, false);
}

// Raw barrier: LDS-ordering only — NO vmcnt drain (this is the whole point:
// xp loads / out stores stay in flight across barriers; no cross-wave vmem deps).
#define BAR_LDS()                                            \
  do {                                                       \
    __builtin_amdgcn_sched_barrier(0);                       \
    asm volatile("s_waitcnt lgkmcnt(0)" ::: "memory");       \
    __builtin_amdgcn_s_barrier();                            \
    __builtin_amdgcn_sched_barrier(0);                       \
  } while (0)

// ---------------------------------------------------------------------------
// prep: f16 weight conversion, pair-transposed Whh, bias sums.
// ---------------------------------------------------------------------------
__global__ void prep_kernel(const float* __restrict__ Wih_f, const float* __restrict__ Whh_f,
                            const float* __restrict__ bih_f, const float* __restrict__ bhh_f,
                            const float* __restrict__ Wih_b, const float* __restrict__ Whh_b,
                            const float* __restrict__ bih_b, const float* __restrict__ bhh_b,
                            _Float16* __restrict__ wi16, uint32_t* __restrict__ whT,
                            float* __restrict__ bsum) {
  int i = blockIdx.x * 256 + threadIdx.x;
  if (i < 2 * 512 * 512) {
    const float* s = (i < 512 * 512) ? Wih_f : Wih_b;
    wi16[i] = (_Float16)s[i & (512 * 512 - 1)];
  }
  if (i < 2 * 256 * 512) {
    int d = i >> 17; int rem = i & ((1 << 17) - 1);
    int kp = rem >> 9; int j = rem & 511;
    const float* W = d ? Whh_b : Whh_f;
    h2 p; p[0] = (_Float16)W[j * 512 + 2 * kp]; p[1] = (_Float16)W[j * 512 + 2 * kp + 1];
    whT[i] = __builtin_bit_cast(uint32_t, p);
  }
  if (i < 2 * 512) {
    int d = i >> 9, j = i & 511;
    bsum[i] = d ? (bih_b[j] + bhh_b[j]) : (bih_f[j] + bhh_f[j]);
  }
}

// ---------------------------------------------------------------------------
// xp_gemm (unchanged): xp[dir][m][n] f16, m = b*1024 + t (processing order).
// ---------------------------------------------------------------------------
__global__ __launch_bounds__(256) void xp_gemm(const float* __restrict__ x,
                                               const _Float16* __restrict__ wi,
                                               const float* __restrict__ bsum,
                                               _Float16* __restrict__ xp) {
  __shared__ _Float16 As[128][40];
  __shared__ _Float16 Bs[128][40];
  const int mt = blockIdx.x, nt = blockIdx.y, dir = blockIdx.z;
  const int m0 = mt * 128, n0 = nt * 128;
  const int tid = threadIdx.x;
  const int lane = tid & 63, w = tid >> 6;
  const int wr = w >> 1, wc = w & 1;
  const int ra = tid >> 1, hf = tid & 1;

  const int mrow = m0 + ra;
  const int bb = mrow >> 10, pp = mrow & 1023;
  const int srow = dir ? ((bb << 10) + (1023 - pp)) : mrow;
  const float*    xbase = x + (size_t)srow * 512 + hf * 16;
  const _Float16* wbase = wi + (size_t)dir * 512 * 512 + (size_t)(n0 + ra) * 512 + hf * 16;

  f4 acc[4][4];
  #pragma unroll
  for (int a = 0; a < 4; ++a)
    #pragma unroll
    for (int b = 0; b < 4; ++b) acc[a][b] = (f4)0.f;

  for (int k0 = 0; k0 < 512; k0 += 32) {
    f4 x0 = *(const f4*)(xbase + k0);
    f4 x1 = *(const f4*)(xbase + k0 + 4);
    f4 x2 = *(const f4*)(xbase + k0 + 8);
    f4 x3 = *(const f4*)(xbase + k0 + 12);
    h8 b0 = *(const h8*)(wbase + k0);
    h8 b1 = *(const h8*)(wbase + k0 + 8);
    h8 a0, a1;
    #pragma unroll
    for (int u = 0; u < 4; ++u) {
      a0[u] = (_Float16)x0[u]; a0[4 + u] = (_Float16)x1[u];
      a1[u] = (_Float16)x2[u]; a1[4 + u] = (_Float16)x3[u];
    }
    __syncthreads();
    *(h8*)&As[ra][hf * 16]     = a0;
    *(h8*)&As[ra][hf * 16 + 8] = a1;
    *(h8*)&Bs[ra][hf * 16]     = b0;
    *(h8*)&Bs[ra][hf * 16 + 8] = b1;
    __syncthreads();
    h8 af[4], bf[4];
    #pragma unroll
    for (int fm = 0; fm < 4; ++fm)
      af[fm] = *(const h8*)&As[wr * 64 + fm * 16 + (lane & 15)][(lane >> 4) * 8];
    #pragma unroll
    for (int fn = 0; fn < 4; ++fn)
      bf[fn] = *(const h8*)&Bs[wc * 64 + fn * 16 + (lane & 15)][(lane >> 4) * 8];
    #pragma unroll
    for (int fm = 0; fm < 4; ++fm)
      #pragma unroll
      for (int fn = 0; fn < 4; ++fn)
        acc[fm][fn] = __builtin_amdgcn_mfma_f32_16x16x32_f16(af[fm], bf[fn], acc[fm][fn], 0, 0, 0);
  }

  float bsv[4];
  #pragma unroll
  for (int fn = 0; fn < 4; ++fn)
    bsv[fn] = bsum[dir * 512 + n0 + wc * 64 + fn * 16 + (lane & 15)];
  #pragma unroll
  for (int fm = 0; fm < 4; ++fm)
    #pragma unroll
    for (int fn = 0; fn < 4; ++fn)
      #pragma unroll
      for (int u = 0; u < 4; ++u) {
        int m = m0 + wr * 64 + fm * 16 + (lane >> 4) * 4 + u;
        int n = n0 + wc * 64 + fn * 16 + (lane & 15);
        xp[((size_t)dir << 25) + (size_t)m * 512 + n] = (_Float16)(acc[fm][fn][u] + bsv[fn]);
      }
}

// ---------------------------------------------------------------------------
// rnn_rec: ONE workgroup per chain (128 WGs, 1024 threads, 1 block/CU).
//   Register budget is 128/wave at 4 waves/SIMD (2048 regs/lane/CU) — so:
//   lane l (q = l>>8 quarter of kp, r = l&255):
//     j0 = r      : kp q*64..q*64+63  -> w0[64]  in registers
//     j1 = 256+r  : kp q*64..q*64+31  -> w1[32]  in registers
//                   kp q*64+32..+63   -> LDS wl, lane-major + XOR swizzle,
//                                        read as 8x ds_read_b128
//   96 regs weights + ~20 working <= 128: no spill (r1-verified).
//   Barriers are RAW (lgkmcnt-only): xp loads & out stores never drain at
//   barriers -> removes ~1000-1500 cyc/step of serialized memory latency.
// ---------------------------------------------------------------------------
__global__ __launch_bounds__(1024, 4) void rnn_rec(const _Float16* __restrict__ xp,
                                                   const uint32_t* __restrict__ whT,
                                                   float* __restrict__ out) {
  extern __shared__ char smem[];
  uint32_t* wl   = (uint32_t*)smem;              // 128 KB, lane-major, swizzled
  uint32_t* hl   = (uint32_t*)(smem + 131072);   // h(t): 256 f16x2 pairs
  float*    psum = (float*)(smem + 132096);      // [4][520]

  const int bid = blockIdx.x;
  const int dir = bid & 1, b = bid >> 1;
  const int l = threadIdx.x;
  const int q = l >> 8, r = l & 255;

  const uint32_t* wb = whT + dir * (256 * 512) + (q * 64) * 512 + r;
  uint32_t w0[64], w1[32];
  #pragma unroll
  for (int p = 0; p < 64; ++p) w0[p] = wb[p * 512];
  #pragma unroll
  for (int p = 0; p < 32; ++p) w1[p] = wb[p * 512 + 256];

  // stage LDS weights: lane-major [l][32 u32], XOR-swizzled 16B slots
  char* wlb = (char*)wl + l * 128;
  const int swz = (l & 7) << 4;
  #pragma unroll
  for (int g = 0; g < 8; ++g) {
    u4 v;
    #pragma unroll
    for (int i = 0; i < 4; ++i) v[i] = wb[(32 + g * 4 + i) * 512 + 256];
    *(u4*)(wlb + ((g * 16) ^ swz)) = v;
  }
  if (l < 256) hl[l] = 0;
  __syncthreads();

  const _Float16* xpp = xp + ((size_t)dir << 25) + ((size_t)b << 19);
  float* op = out + (((size_t)(b * 2 + dir)) << 19);

  for (int t = 0; t < TSTEPS; ++t) {
    // xp prefetch: consumed in the epilogue; never drained at a barrier.
    float xpv = 0.f;
    if (l < 512) xpv = (float)xpp[(size_t)t * 512 + l];

    float acc0 = 0.f, acc1 = 0.f;
    const uint32_t* hq = hl + q * 64;
    #pragma unroll
    for (int cb = 0; cb < 16; ++cb) {
      u4 hv = *(const u4*)(hq + cb * 4);            // wave-uniform broadcast
      if (cb < 8) {
        #pragma unroll
        for (int i = 0; i < 4; ++i) {
          acc0 = fdot2(w0[cb * 4 + i], hv[i], acc0);
          acc1 = fdot2(w1[cb * 4 + i], hv[i], acc1);
        }
      } else {
        u4 wv = *(const u4*)(wlb + ((((cb - 8) * 16)) ^ swz));   // b128, swizzled
        #pragma unroll
        for (int i = 0; i < 4; ++i) {
          acc0 = fdot2(w0[cb * 4 + i], hv[i], acc0);
          acc1 = fdot2(wv[i], hv[i], acc1);
        }
      }
    }
    psum[q * 520 + r]       = acc0;   // lanes consecutive -> conflict-free
    psum[q * 520 + 256 + r] = acc1;
    BAR_LDS();                                      // B1 (no vmcnt drain)

    if (l < 512) {
      float s = psum[l] + psum[520 + l] + psum[1040 + l] + psum[1560 + l] + xpv;
      float e = __expf(2.f * s);
      float hv = 1.f - 2.f * __builtin_amdgcn_rcpf(e + 1.f);    // tanh(s)
      op[(size_t)t * 512 + l] = hv;                 // fire-and-forget store
      ((_Float16*)hl)[l] = (_Float16)hv;
    }
    BAR_LDS();                                      // B2: h(t) ready in LDS
  }
}

// ---------------------------------------------------------------------------
extern "C" void kernel_launch(void* const* d_in, const int* in_sizes, int n_in,
                              void* d_out, int out_size, void* d_ws, size_t ws_size,
                              hipStream_t stream) {
  const float* x     = (const float*)d_in[0];
  const float* Wih_f = (const float*)d_in[1];
  const float* Whh_f = (const float*)d_in[2];
  const float* bih_f = (const float*)d_in[3];
  const float* bhh_f = (const float*)d_in[4];
  const float* Wih_b = (const float*)d_in[5];
  const float* Whh_b = (const float*)d_in[6];
  const float* bih_b = (const float*)d_in[7];
  const float* bhh_b = (const float*)d_in[8];

  char* ws = (char*)d_ws;
  _Float16* xp16 = (_Float16*)ws;                 // 128 MB
  _Float16* wi16 = (_Float16*)(ws + 134217728);   // 1 MB
  uint32_t* whT  = (uint32_t*)(ws + 135266304);   // 1 MB
  float*    bsum = (float*)(ws + 136314880);      // 4 KB
  float* out = (float*)d_out;

  prep_kernel<<<2048, 256, 0, stream>>>(Wih_f, Whh_f, bih_f, bhh_f,
                                        Wih_b, Whh_b, bih_b, bhh_b, wi16, whT, bsum);
  dim3 g(512, 4, 2);
  xp_gemm<<<g, 256, 0, stream>>>(x, wi16, bsum, xp16);

  const int REC_LDS = 140416;  // 128K wl + 1K hl + 8.3K psum
  hipFuncSetAttribute((const void*)rnn_rec, hipFuncAttributeMaxDynamicSharedMemorySize, REC_LDS);
  rnn_rec<<<128, 1024, REC_LDS, stream>>>(xp16, whT, out);
}

// Round 5
// 1568.006 us; speedup vs baseline: 5.4383x; 1.0480x over previous
//
#include <hip/hip_runtime.h>
#include <hip/hip_fp16.h>
#include <cstdint>

typedef _Float16 h2 __attribute__((ext_vector_type(2)));
typedef _Float16 h8 __attribute__((ext_vector_type(8)));
typedef float    f4 __attribute__((ext_vector_type(4)));
typedef uint32_t u4 __attribute__((ext_vector_type(4)));

#define BATCH 64
#define TSTEPS 1024
#define DDIM 512
#define HDIM 512

static __device__ __forceinline__ float fdot2(uint32_t w, uint32_t h, float acc) {
  return __builtin_amdgcn_fdot2(__builtin_bit_cast(h2, w), __builtin_bit_cast(h2, h), acc, false);
}

// Raw barrier: LDS-ordering only — NO vmcnt drain (xp loads / out stores stay
// in flight across barriers; no cross-wave vmem deps). Verified win in r4.
#define BAR_LDS()                                            \
  do {                                                       \
    __builtin_amdgcn_sched_barrier(0);                       \
    asm volatile("s_waitcnt lgkmcnt(0)" ::: "memory");       \
    __builtin_amdgcn_s_barrier();                            \
    __builtin_amdgcn_sched_barrier(0);                       \
  } while (0)

// ---------------------------------------------------------------------------
// prep: f16 weight conversion, pair-transposed Whh, bias sums.
// ---------------------------------------------------------------------------
__global__ void prep_kernel(const float* __restrict__ Wih_f, const float* __restrict__ Whh_f,
                            const float* __restrict__ bih_f, const float* __restrict__ bhh_f,
                            const float* __restrict__ Wih_b, const float* __restrict__ Whh_b,
                            const float* __restrict__ bih_b, const float* __restrict__ bhh_b,
                            _Float16* __restrict__ wi16, uint32_t* __restrict__ whT,
                            float* __restrict__ bsum) {
  int i = blockIdx.x * 256 + threadIdx.x;
  if (i < 2 * 512 * 512) {
    const float* s = (i < 512 * 512) ? Wih_f : Wih_b;
    wi16[i] = (_Float16)s[i & (512 * 512 - 1)];
  }
  if (i < 2 * 256 * 512) {
    int d = i >> 17; int rem = i & ((1 << 17) - 1);
    int kp = rem >> 9; int j = rem & 511;
    const float* W = d ? Whh_b : Whh_f;
    h2 p; p[0] = (_Float16)W[j * 512 + 2 * kp]; p[1] = (_Float16)W[j * 512 + 2 * kp + 1];
    whT[i] = __builtin_bit_cast(uint32_t, p);
  }
  if (i < 2 * 512) {
    int d = i >> 9, j = i & 511;
    bsum[i] = d ? (bih_b[j] + bhh_b[j]) : (bih_f[j] + bhh_f[j]);
  }
}

// ---------------------------------------------------------------------------
// xp_gemm (unchanged): xp[dir][m][n] f16, m = b*1024 + t (processing order).
// ---------------------------------------------------------------------------
__global__ __launch_bounds__(256) void xp_gemm(const float* __restrict__ x,
                                               const _Float16* __restrict__ wi,
                                               const float* __restrict__ bsum,
                                               _Float16* __restrict__ xp) {
  __shared__ _Float16 As[128][40];
  __shared__ _Float16 Bs[128][40];
  const int mt = blockIdx.x, nt = blockIdx.y, dir = blockIdx.z;
  const int m0 = mt * 128, n0 = nt * 128;
  const int tid = threadIdx.x;
  const int lane = tid & 63, w = tid >> 6;
  const int wr = w >> 1, wc = w & 1;
  const int ra = tid >> 1, hf = tid & 1;

  const int mrow = m0 + ra;
  const int bb = mrow >> 10, pp = mrow & 1023;
  const int srow = dir ? ((bb << 10) + (1023 - pp)) : mrow;
  const float*    xbase = x + (size_t)srow * 512 + hf * 16;
  const _Float16* wbase = wi + (size_t)dir * 512 * 512 + (size_t)(n0 + ra) * 512 + hf * 16;

  f4 acc[4][4];
  #pragma unroll
  for (int a = 0; a < 4; ++a)
    #pragma unroll
    for (int b = 0; b < 4; ++b) acc[a][b] = (f4)0.f;

  for (int k0 = 0; k0 < 512; k0 += 32) {
    f4 x0 = *(const f4*)(xbase + k0);
    f4 x1 = *(const f4*)(xbase + k0 + 4);
    f4 x2 = *(const f4*)(xbase + k0 + 8);
    f4 x3 = *(const f4*)(xbase + k0 + 12);
    h8 b0 = *(const h8*)(wbase + k0);
    h8 b1 = *(const h8*)(wbase + k0 + 8);
    h8 a0, a1;
    #pragma unroll
    for (int u = 0; u < 4; ++u) {
      a0[u] = (_Float16)x0[u]; a0[4 + u] = (_Float16)x1[u];
      a1[u] = (_Float16)x2[u]; a1[4 + u] = (_Float16)x3[u];
    }
    __syncthreads();
    *(h8*)&As[ra][hf * 16]     = a0;
    *(h8*)&As[ra][hf * 16 + 8] = a1;
    *(h8*)&Bs[ra][hf * 16]     = b0;
    *(h8*)&Bs[ra][hf * 16 + 8] = b1;
    __syncthreads();
    h8 af[4], bf[4];
    #pragma unroll
    for (int fm = 0; fm < 4; ++fm)
      af[fm] = *(const h8*)&As[wr * 64 + fm * 16 + (lane & 15)][(lane >> 4) * 8];
    #pragma unroll
    for (int fn = 0; fn < 4; ++fn)
      bf[fn] = *(const h8*)&Bs[wc * 64 + fn * 16 + (lane & 15)][(lane >> 4) * 8];
    #pragma unroll
    for (int fm = 0; fm < 4; ++fm)
      #pragma unroll
      for (int fn = 0; fn < 4; ++fn)
        acc[fm][fn] = __builtin_amdgcn_mfma_f32_16x16x32_f16(af[fm], bf[fn], acc[fm][fn], 0, 0, 0);
  }

  float bsv[4];
  #pragma unroll
  for (int fn = 0; fn < 4; ++fn)
    bsv[fn] = bsum[dir * 512 + n0 + wc * 64 + fn * 16 + (lane & 15)];
  #pragma unroll
  for (int fm = 0; fm < 4; ++fm)
    #pragma unroll
    for (int fn = 0; fn < 4; ++fn)
      #pragma unroll
      for (int u = 0; u < 4; ++u) {
        int m = m0 + wr * 64 + fm * 16 + (lane >> 4) * 4 + u;
        int n = n0 + wc * 64 + fn * 16 + (lane & 15);
        xp[((size_t)dir << 25) + (size_t)m * 512 + n] = (_Float16)(acc[fm][fn][u] + bsv[fn]);
      }
}

// ---------------------------------------------------------------------------
// rnn_rec: ONE workgroup per chain (128 WGs, 1024 threads, 1 block/CU).
//   lane l (q = l>>8, r = l&255):
//     j0 = r      : kp q*64..q*64+63  -> w0[64] in registers
//     j1 = 256+r  : kp q*64..q*64+31  -> w1[32] in registers
//                   kp q*64+32..+63   -> LDS wl (group-contiguous, see below)
//   wl layout (r5 fix): addr = (l>>3)*1024 + g*128 + (l&7)*16.
//   Each 8-lane group's b128 read covers 128 contiguous B = all 32 banks once;
//   16-lane phase = 2 lanes/bank (free 2-way, m136). r4's lane-major+XOR gave
//   8-way conflicts (6.7e7 = 512 cyc/step) because l and l+8 shared a slot.
//   g*128 <= 896 fits the 16-bit ds offset immediate -> one base reg, 8 imms.
// ---------------------------------------------------------------------------
__global__ __launch_bounds__(1024, 4) void rnn_rec(const _Float16* __restrict__ xp,
                                                   const uint32_t* __restrict__ whT,
                                                   float* __restrict__ out) {
  extern __shared__ char smem[];
  uint32_t* wl   = (uint32_t*)smem;              // 128 KB, group-contiguous
  uint32_t* hl   = (uint32_t*)(smem + 131072);   // h(t): 256 f16x2 pairs
  float*    psum = (float*)(smem + 132096);      // [4][520]

  const int bid = blockIdx.x;
  const int dir = bid & 1, b = bid >> 1;
  const int l = threadIdx.x;
  const int q = l >> 8, r = l & 255;

  const uint32_t* wb = whT + dir * (256 * 512) + (q * 64) * 512 + r;
  uint32_t w0[64], w1[32];
  #pragma unroll
  for (int p = 0; p < 64; ++p) w0[p] = wb[p * 512];
  #pragma unroll
  for (int p = 0; p < 32; ++p) w1[p] = wb[p * 512 + 256];

  // stage LDS weights: group-contiguous, conflict-free for b128 read & write
  char* wlb = (char*)wl + (l >> 3) * 1024 + (l & 7) * 16;
  #pragma unroll
  for (int g = 0; g < 8; ++g) {
    u4 v;
    #pragma unroll
    for (int i = 0; i < 4; ++i) v[i] = wb[(32 + g * 4 + i) * 512 + 256];
    *(u4*)(wlb + g * 128) = v;
  }
  if (l < 256) hl[l] = 0;
  __syncthreads();

  const _Float16* xpp = xp + ((size_t)dir << 25) + ((size_t)b << 19);
  float* op = out + (((size_t)(b * 2 + dir)) << 19);

  for (int t = 0; t < TSTEPS; ++t) {
    // xp prefetch: consumed in the epilogue; never drained at a barrier.
    float xpv = 0.f;
    if (l < 512) xpv = (float)xpp[(size_t)t * 512 + l];

    float acc0 = 0.f, acc1 = 0.f;
    const uint32_t* hq = hl + q * 64;
    #pragma unroll
    for (int cb = 0; cb < 16; ++cb) {
      u4 hv = *(const u4*)(hq + cb * 4);            // wave-uniform broadcast
      if (cb < 8) {
        #pragma unroll
        for (int i = 0; i < 4; ++i) {
          acc0 = fdot2(w0[cb * 4 + i], hv[i], acc0);
          acc1 = fdot2(w1[cb * 4 + i], hv[i], acc1);
        }
      } else {
        u4 wv = *(const u4*)(wlb + (cb - 8) * 128);  // b128, conflict-free
        #pragma unroll
        for (int i = 0; i < 4; ++i) {
          acc0 = fdot2(w0[cb * 4 + i], hv[i], acc0);
          acc1 = fdot2(wv[i], hv[i], acc1);
        }
      }
    }
    psum[q * 520 + r]       = acc0;   // lanes consecutive -> conflict-free
    psum[q * 520 + 256 + r] = acc1;
    BAR_LDS();                                      // B1 (no vmcnt drain)

    if (l < 512) {
      float s = psum[l] + psum[520 + l] + psum[1040 + l] + psum[1560 + l] + xpv;
      float e = __expf(2.f * s);
      float hv = 1.f - 2.f * __builtin_amdgcn_rcpf(e + 1.f);    // tanh(s)
      op[(size_t)t * 512 + l] = hv;                 // fire-and-forget store
      ((_Float16*)hl)[l] = (_Float16)hv;
    }
    BAR_LDS();                                      // B2: h(t) ready in LDS
  }
}

// ---------------------------------------------------------------------------
extern "C" void kernel_launch(void* const* d_in, const int* in_sizes, int n_in,
                              void* d_out, int out_size, void* d_ws, size_t ws_size,
                              hipStream_t stream) {
  const float* x     = (const float*)d_in[0];
  const float* Wih_f = (const float*)d_in[1];
  const float* Whh_f = (const float*)d_in[2];
  const float* bih_f = (const float*)d_in[3];
  const float* bhh_f = (const float*)d_in[4];
  const float* Wih_b = (const float*)d_in[5];
  const float* Whh_b = (const float*)d_in[6];
  const float* bih_b = (const float*)d_in[7];
  const float* bhh_b = (const float*)d_in[8];

  char* ws = (char*)d_ws;
  _Float16* xp16 = (_Float16*)ws;                 // 128 MB
  _Float16* wi16 = (_Float16*)(ws + 134217728);   // 1 MB
  uint32_t* whT  = (uint32_t*)(ws + 135266304);   // 1 MB
  float*    bsum = (float*)(ws + 136314880);      // 4 KB
  float* out = (float*)d_out;

  prep_kernel<<<2048, 256, 0, stream>>>(Wih_f, Whh_f, bih_f, bhh_f,
                                        Wih_b, Whh_b, bih_b, bhh_b, wi16, whT, bsum);
  dim3 g(512, 4, 2);
  xp_gemm<<<g, 256, 0, stream>>>(x, wi16, bsum, xp16);

  const int REC_LDS = 140416;  // 128K wl + 1K hl + 8.3K psum
  hipFuncSetAttribute((const void*)rnn_rec, hipFuncAttributeMaxDynamicSharedMemorySize, REC_LDS);
  rnn_rec<<<128, 1024, REC_LDS, stream>>>(xp16, whT, out);
}